// Round 5
// baseline (663.677 us; speedup 1.0000x reference)
//
#include <hip/hip_runtime.h>
#include <math.h>

typedef float  f4v __attribute__((ext_vector_type(4)));
typedef short  s8v __attribute__((ext_vector_type(8)));

__device__ __forceinline__ float sigm(float x) { return 1.f / (1.f + expf(-x)); }
__device__ __forceinline__ unsigned short f2bf(float f) {
    unsigned int u = __float_as_uint(f);
    return (unsigned short)((u + 0x7FFF + ((u >> 16) & 1)) >> 16);   // RTNE
}
__device__ __forceinline__ s8v pack8(float4 a, float4 b) {
    union { unsigned short u[8]; s8v v; } r;
    r.u[0] = f2bf(a.x); r.u[1] = f2bf(a.y); r.u[2] = f2bf(a.z); r.u[3] = f2bf(a.w);
    r.u[4] = f2bf(b.x); r.u[5] = f2bf(b.y); r.u[6] = f2bf(b.z); r.u[7] = f2bf(b.w);
    return r.v;
}
__device__ __forceinline__ s8v pack8s(float4 a, float4 b, float m) {
    union { unsigned short u[8]; s8v v; } r;
    r.u[0] = f2bf(a.x * m); r.u[1] = f2bf(a.y * m); r.u[2] = f2bf(a.z * m); r.u[3] = f2bf(a.w * m);
    r.u[4] = f2bf(b.x * m); r.u[5] = f2bf(b.y * m); r.u[6] = f2bf(b.z * m); r.u[7] = f2bf(b.w * m);
    return r.v;
}

// ---------------- prep: pack weights to bf16 [N][K] layouts ----------------
// W2p[64][512]; W3p[64][64][16] (3x3 padded to 16, zeros); Wfcp[512][3136]; Wihp[1024][512];
// W1p[32][192] with 1/255 folded.
__global__ __launch_bounds__(256) void k_prep(const float* __restrict__ W2, const float* __restrict__ W3,
                                              const float* __restrict__ Wfc, const float* __restrict__ Wih,
                                              const float* __restrict__ W1,
                                              unsigned short* __restrict__ W2p, unsigned short* __restrict__ W3p,
                                              unsigned short* __restrict__ Wfcp, unsigned short* __restrict__ Wihp,
                                              unsigned short* __restrict__ W1p) {
    int i = blockIdx.x * 256 + threadIdx.x;
    if (i < 32768) {
        W2p[i] = f2bf(W2[i]);
    } else if (i < 98304) {
        int j = i - 32768;
        int co = j >> 10, r = j & 1023, ci = r >> 4, s = r & 15, ky = s >> 2, kx = s & 3;
        W3p[j] = (ky < 3 && kx < 3) ? f2bf(W3[((co * 64 + ci) * 3 + ky) * 3 + kx]) : (unsigned short)0;
    } else if (i < 1703936) {
        int j = i - 98304;
        Wfcp[j] = f2bf(Wfc[j]);
    } else if (i < 2228224) {
        int j = i - 1703936;
        int n = j >> 9, k = j & 511;
        Wihp[j] = f2bf(Wih[n * 517 + k]);
    } else if (i < 2234368) {
        int j = i - 2228224;                       // [32][192] natural OIHW flat
        W1p[j] = f2bf(W1[j] * (1.f / 255.f));
    }
}

// ---------------- conv1 (MFMA): M=409600 pixels, N=32, K=192 (c*64+ky*8+kx) ----------------
// A read directly from fp32 image (aligned float4 pairs), packed bf16 in-reg. 1/255 folded into W1p.
__global__ __launch_bounds__(256) void k_conv1(const float* __restrict__ img,
                                               const unsigned short* __restrict__ Bw,
                                               const float* __restrict__ bias,
                                               unsigned short* __restrict__ out) {
    int lane = threadIdx.x & 63, w = threadIdx.x >> 6;
    int l15 = lane & 15, q = lane >> 4;
    int m0 = blockIdx.x * 128 + w * 32;
    int ma = m0 + l15, mb = ma + 16;
    int ia = ma / 400, pa = ma - ia * 400; int oya = pa / 20, oxa = pa - oya * 20;
    int ib = mb / 400, pb = mb - ib * 400; int oyb = pb / 20, oxb = pb - oyb * 20;
    const float* Aa = img + ia * 21168 + oya * 336 + oxa * 4;   // 336 = 4*84 (stride-4 rows)
    const float* Ab = img + ib * 21168 + oyb * 336 + oxb * 4;
    const unsigned short* Bp0 = Bw + l15 * 192 + q * 8;
    const unsigned short* Bp1 = Bw + (16 + l15) * 192 + q * 8;
    s8v bf0[6], bf1[6];
#pragma unroll
    for (int ks = 0; ks < 6; ++ks) {
        bf0[ks] = *(const s8v*)(Bp0 + ks * 32);
        bf1[ks] = *(const s8v*)(Bp1 + ks * 32);
    }
    f4v acc[4];
#pragma unroll
    for (int i = 0; i < 4; ++i) acc[i] = (f4v){0.f, 0.f, 0.f, 0.f};
#pragma unroll
    for (int ks = 0; ks < 6; ++ks) {
        int k0 = ks * 32 + q * 8;
        int c = k0 >> 6, ky = (k0 >> 3) & 7;
        const float* ra = Aa + c * 7056 + ky * 84;
        const float* rb = Ab + c * 7056 + ky * 84;
        float4 a0 = *(const float4*)(ra), a1 = *(const float4*)(ra + 4);
        float4 b0 = *(const float4*)(rb), b1 = *(const float4*)(rb + 4);
        s8v ua = pack8(a0, a1);
        s8v ub = pack8(b0, b1);
        acc[0] = __builtin_amdgcn_mfma_f32_16x16x32_bf16(ua, bf0[ks], acc[0], 0, 0, 0);
        acc[1] = __builtin_amdgcn_mfma_f32_16x16x32_bf16(ua, bf1[ks], acc[1], 0, 0, 0);
        acc[2] = __builtin_amdgcn_mfma_f32_16x16x32_bf16(ub, bf0[ks], acc[2], 0, 0, 0);
        acc[3] = __builtin_amdgcn_mfma_f32_16x16x32_bf16(ub, bf1[ks], acc[3], 0, 0, 0);
    }
#pragma unroll
    for (int mf = 0; mf < 2; ++mf) {
#pragma unroll
        for (int r = 0; r < 4; ++r) {
            int m = m0 + mf * 16 + q * 4 + r;
            int im = m / 400, p = m - im * 400;
            int oy = p / 20, ox = p - oy * 20;
#pragma unroll
            for (int nf = 0; nf < 2; ++nf) {
                int n = nf * 16 + l15;
                float v = acc[mf * 2 + nf][r] + bias[n];
                out[((im * 32 + n) * 20 + oy) * 20 + ox] = f2bf(v > 0.f ? v : 0.f);
            }
        }
    }
}

// ---------------- conv2 (MFMA): M=82944, N=64, K=512 ----------------
__global__ __launch_bounds__(256) void k_conv2(const unsigned short* __restrict__ A,
                                               const unsigned short* __restrict__ Bw,
                                               const float* __restrict__ bias,
                                               unsigned short* __restrict__ out) {
    int lane = threadIdx.x & 63, w = threadIdx.x >> 6;
    int l15 = lane & 15, q = lane >> 4;
    int m0 = blockIdx.x * 128 + w * 32;
    int ma = m0 + l15, mb = ma + 16;
    int ia = ma / 81, pa = ma - ia * 81; int oya = pa / 9, oxa = pa - oya * 9;
    int ib = mb / 81, pb = mb - ib * 81; int oyb = pb / 9, oxb = pb - oyb * 9;
    const unsigned short* Aa = A + ia * 12800 + oya * 40 + oxa * 2 + (q & 1) * 40;
    const unsigned short* Ab = A + ib * 12800 + oyb * 40 + oxb * 2 + (q & 1) * 40;
    int ci0 = q >> 1;
    const unsigned short* B0 = Bw + (l15) * 512 + q * 8;
    const unsigned short* B1 = Bw + (16 + l15) * 512 + q * 8;
    const unsigned short* B2 = Bw + (32 + l15) * 512 + q * 8;
    const unsigned short* B3 = Bw + (48 + l15) * 512 + q * 8;
    f4v acc[8];
#pragma unroll
    for (int i = 0; i < 8; ++i) acc[i] = (f4v){0.f, 0.f, 0.f, 0.f};
    for (int c = 0; c < 16; ++c) {
        int ci = 2 * c + ci0;
        const unsigned short* pa_ = Aa + ci * 400;
        const unsigned short* pb_ = Ab + ci * 400;
        union { unsigned int u[4]; s8v v; } ua, ub;
        ua.u[0] = *(const unsigned int*)(pa_);      ua.u[1] = *(const unsigned int*)(pa_ + 2);
        ua.u[2] = *(const unsigned int*)(pa_ + 20); ua.u[3] = *(const unsigned int*)(pa_ + 22);
        ub.u[0] = *(const unsigned int*)(pb_);      ub.u[1] = *(const unsigned int*)(pb_ + 2);
        ub.u[2] = *(const unsigned int*)(pb_ + 20); ub.u[3] = *(const unsigned int*)(pb_ + 22);
        s8v b0 = *(const s8v*)B0, b1 = *(const s8v*)B1, b2 = *(const s8v*)B2, b3 = *(const s8v*)B3;
        B0 += 32; B1 += 32; B2 += 32; B3 += 32;
        acc[0] = __builtin_amdgcn_mfma_f32_16x16x32_bf16(ua.v, b0, acc[0], 0, 0, 0);
        acc[1] = __builtin_amdgcn_mfma_f32_16x16x32_bf16(ua.v, b1, acc[1], 0, 0, 0);
        acc[2] = __builtin_amdgcn_mfma_f32_16x16x32_bf16(ua.v, b2, acc[2], 0, 0, 0);
        acc[3] = __builtin_amdgcn_mfma_f32_16x16x32_bf16(ua.v, b3, acc[3], 0, 0, 0);
        acc[4] = __builtin_amdgcn_mfma_f32_16x16x32_bf16(ub.v, b0, acc[4], 0, 0, 0);
        acc[5] = __builtin_amdgcn_mfma_f32_16x16x32_bf16(ub.v, b1, acc[5], 0, 0, 0);
        acc[6] = __builtin_amdgcn_mfma_f32_16x16x32_bf16(ub.v, b2, acc[6], 0, 0, 0);
        acc[7] = __builtin_amdgcn_mfma_f32_16x16x32_bf16(ub.v, b3, acc[7], 0, 0, 0);
    }
#pragma unroll
    for (int mf = 0; mf < 2; ++mf) {
        int mt = m0 + mf * 16 + q * 4;
#pragma unroll
        for (int r = 0; r < 4; ++r) {
            int m = mt + r; int im = m / 81, p = m - im * 81;
#pragma unroll
            for (int nf = 0; nf < 4; ++nf) {
                int n = nf * 16 + l15;
                float v = acc[mf * 4 + nf][r] + bias[n];
                out[im * 5184 + n * 81 + p] = f2bf(v > 0.f ? v : 0.f);
            }
        }
    }
}

// ---------------- conv3 (MFMA): M=50176, N=64, K=64ci*16slots ----------------
__global__ __launch_bounds__(256) void k_conv3(const unsigned short* __restrict__ A,
                                               const unsigned short* __restrict__ Bw,
                                               const float* __restrict__ bias,
                                               unsigned short* __restrict__ out) {
    int lane = threadIdx.x & 63, w = threadIdx.x >> 6;
    int l15 = lane & 15, q = lane >> 4;
    int m0 = blockIdx.x * 128 + w * 32;
    int ma = m0 + l15, mb = ma + 16;
    int ia = ma / 49, pa = ma - ia * 49; int oya = pa / 7, oxa = pa - oya * 7;
    int ib = mb / 49, pb = mb - ib * 49; int oyb = pb / 7, oxb = pb - oyb * 7;
    int ky0 = (q & 1) * 2;
    int r0off = ky0 * 9;
    int r1off = (ky0 + 1 > 2 ? 2 : ky0 + 1) * 9;
    int zr = q & 1;
    const unsigned short* Aa = A + ia * 5184 + oya * 9 + oxa;
    const unsigned short* Ab = A + ib * 5184 + oyb * 9 + oxb;
    int ci0 = q >> 1;
    const unsigned short* B0 = Bw + (l15) * 1024 + q * 8;
    const unsigned short* B1 = Bw + (16 + l15) * 1024 + q * 8;
    const unsigned short* B2 = Bw + (32 + l15) * 1024 + q * 8;
    const unsigned short* B3 = Bw + (48 + l15) * 1024 + q * 8;
    f4v acc[8];
#pragma unroll
    for (int i = 0; i < 8; ++i) acc[i] = (f4v){0.f, 0.f, 0.f, 0.f};
    for (int c = 0; c < 32; ++c) {
        int ci = 2 * c + ci0;
        const unsigned short* pa_ = Aa + ci * 81;
        const unsigned short* pb_ = Ab + ci * 81;
        s8v av, bv;
        av[0] = pa_[r0off]; av[1] = pa_[r0off + 1]; av[2] = pa_[r0off + 2]; av[3] = 0;
        av[4] = zr ? (short)0 : (short)pa_[r1off];
        av[5] = zr ? (short)0 : (short)pa_[r1off + 1];
        av[6] = zr ? (short)0 : (short)pa_[r1off + 2];
        av[7] = 0;
        bv[0] = pb_[r0off]; bv[1] = pb_[r0off + 1]; bv[2] = pb_[r0off + 2]; bv[3] = 0;
        bv[4] = zr ? (short)0 : (short)pb_[r1off];
        bv[5] = zr ? (short)0 : (short)pb_[r1off + 1];
        bv[6] = zr ? (short)0 : (short)pb_[r1off + 2];
        bv[7] = 0;
        s8v b0 = *(const s8v*)B0, b1 = *(const s8v*)B1, b2 = *(const s8v*)B2, b3 = *(const s8v*)B3;
        B0 += 32; B1 += 32; B2 += 32; B3 += 32;
        acc[0] = __builtin_amdgcn_mfma_f32_16x16x32_bf16(av, b0, acc[0], 0, 0, 0);
        acc[1] = __builtin_amdgcn_mfma_f32_16x16x32_bf16(av, b1, acc[1], 0, 0, 0);
        acc[2] = __builtin_amdgcn_mfma_f32_16x16x32_bf16(av, b2, acc[2], 0, 0, 0);
        acc[3] = __builtin_amdgcn_mfma_f32_16x16x32_bf16(av, b3, acc[3], 0, 0, 0);
        acc[4] = __builtin_amdgcn_mfma_f32_16x16x32_bf16(bv, b0, acc[4], 0, 0, 0);
        acc[5] = __builtin_amdgcn_mfma_f32_16x16x32_bf16(bv, b1, acc[5], 0, 0, 0);
        acc[6] = __builtin_amdgcn_mfma_f32_16x16x32_bf16(bv, b2, acc[6], 0, 0, 0);
        acc[7] = __builtin_amdgcn_mfma_f32_16x16x32_bf16(bv, b3, acc[7], 0, 0, 0);
    }
#pragma unroll
    for (int mf = 0; mf < 2; ++mf) {
        int mt = m0 + mf * 16 + q * 4;
#pragma unroll
        for (int r = 0; r < 4; ++r) {
            int m = mt + r; int im = m / 49, p = m - im * 49;
#pragma unroll
            for (int nf = 0; nf < 4; ++nf) {
                int n = nf * 16 + l15;
                float v = acc[mf * 4 + nf][r] + bias[n];
                out[im * 3136 + n * 49 + p] = f2bf(v > 0.f ? v : 0.f);
            }
        }
    }
}

// ---------------- FC (MFMA) ----------------
__global__ __launch_bounds__(256) void k_fc(const unsigned short* __restrict__ A,
                                            const unsigned short* __restrict__ Bw,
                                            const float* __restrict__ bias,
                                            unsigned short* __restrict__ out) {
    int lane = threadIdx.x & 63, w = threadIdx.x >> 6;
    int l15 = lane & 15, q = lane >> 4;
    int m0 = blockIdx.x * 32 + (w & 1) * 16;
    int n0 = blockIdx.y * 64 + (w >> 1) * 32;
    const unsigned short* Ap = A + (m0 + l15) * 3136 + q * 8;
    const unsigned short* B0 = Bw + (n0 + l15) * 3136 + q * 8;
    const unsigned short* B1 = B0 + 16 * 3136;
    f4v acc0 = (f4v){0.f, 0.f, 0.f, 0.f}, acc1 = (f4v){0.f, 0.f, 0.f, 0.f};
    for (int c = 0; c < 98; ++c) {
        s8v av = *(const s8v*)Ap;
        s8v b0 = *(const s8v*)B0;
        s8v b1 = *(const s8v*)B1;
        Ap += 32; B0 += 32; B1 += 32;
        acc0 = __builtin_amdgcn_mfma_f32_16x16x32_bf16(av, b0, acc0, 0, 0, 0);
        acc1 = __builtin_amdgcn_mfma_f32_16x16x32_bf16(av, b1, acc1, 0, 0, 0);
    }
    float bi0 = bias[n0 + l15], bi1 = bias[n0 + 16 + l15];
#pragma unroll
    for (int r = 0; r < 4; ++r) {
        int m = m0 + q * 4 + r;
        float v0 = acc0[r] + bi0; v0 = v0 > 0.f ? v0 : 0.f;
        float v1 = acc1[r] + bi1; v1 = v1 > 0.f ? v1 : 0.f;
        out[m * 512 + n0 + l15] = f2bf(v0);
        out[m * 512 + n0 + 16 + l15] = f2bf(v1);
    }
}

// ---------------- gx (MFMA) ----------------
__global__ __launch_bounds__(256) void k_gx(const unsigned short* __restrict__ A,
                                            const unsigned short* __restrict__ Bw,
                                            const float* __restrict__ Wih,
                                            const float* __restrict__ bih,
                                            const float* __restrict__ bhh,
                                            const int* __restrict__ act,
                                            float* __restrict__ out) {
    int lane = threadIdx.x & 63, w = threadIdx.x >> 6;
    int l15 = lane & 15, q = lane >> 4;
    int m0 = blockIdx.x * 32 + (w & 1) * 16;
    int n0 = blockIdx.y * 64 + (w >> 1) * 32;
    const unsigned short* Ap = A + (m0 + l15) * 512 + q * 8;
    const unsigned short* B0 = Bw + (n0 + l15) * 512 + q * 8;
    const unsigned short* B1 = B0 + 16 * 512;
    f4v acc0 = (f4v){0.f, 0.f, 0.f, 0.f}, acc1 = (f4v){0.f, 0.f, 0.f, 0.f};
    for (int c = 0; c < 16; ++c) {
        s8v av = *(const s8v*)Ap;
        s8v b0 = *(const s8v*)B0;
        s8v b1 = *(const s8v*)B1;
        Ap += 32; B0 += 32; B1 += 32;
        acc0 = __builtin_amdgcn_mfma_f32_16x16x32_bf16(av, b0, acc0, 0, 0, 0);
        acc1 = __builtin_amdgcn_mfma_f32_16x16x32_bf16(av, b1, acc1, 0, 0, 0);
    }
    int na = n0 + l15, nb = n0 + 16 + l15;
    float ca = bih[na] + bhh[na], cb_ = bih[nb] + bhh[nb];
#pragma unroll
    for (int r = 0; r < 4; ++r) {
        int m = m0 + q * 4 + r;
        int a = act[m];
        out[m * 1024 + na] = acc0[r] + Wih[na * 517 + 512 + a] + ca;
        out[m * 1024 + nb] = acc1[r] + Wih[nb * 517 + 512 + a] + cb_;
    }
}

// ---------------- fused LSTM: 16 persistent workgroups, device-scope barrier per step ----------------
// wg owns 16 hidden units (hu0=wg*16); wave g (0..3) owns gate g. Whh rows for (gate g, units hu0..hu0+15)
// live in registers as 8 MFMA B-fragments (K=256). Per step: MFMA h(bf16,masked) x Whh-slice,
// gate exchange via LDS, pointwise c/h update, write h slice to hs[t], spin-barrier.
__global__ __launch_bounds__(256) void k_lstm_fused(const float* __restrict__ h0,
                                                    const float* __restrict__ c0,
                                                    const float* __restrict__ done,
                                                    const float* __restrict__ gx,
                                                    const float* __restrict__ Whh,
                                                    float* __restrict__ hs,
                                                    float* __restrict__ cb,
                                                    unsigned int* __restrict__ cnt) {
    int hu0 = blockIdx.x * 16;
    int lane = threadIdx.x & 63, g = threadIdx.x >> 6;
    int l15 = lane & 15, q = lane >> 4;
    __shared__ float gbuf[4][32][16];
    __shared__ float cst[32][16];

    // B-fragments: row = g*256 + hu0 + l15 of Whh[1024][256], k = ks*32 + q*8
    const float* wrow = Whh + (g * 256 + hu0 + l15) * 256 + q * 8;
    s8v bfr[8];
#pragma unroll
    for (int ks = 0; ks < 8; ++ks) {
        float4 w0 = *(const float4*)(wrow + ks * 32);
        float4 w1 = *(const float4*)(wrow + ks * 32 + 4);
        bfr[ks] = pack8(w0, w1);
    }
    for (int i = threadIdx.x; i < 512; i += 256) {
        int b = i >> 4, u = i & 15;
        cst[b][u] = c0[b * 256 + hu0 + u];
    }
    __syncthreads();

    for (int t = 0; t < 32; ++t) {
        const float* hsrc = t ? (hs + (t - 1) * 8192) : h0;
        float mA = 1.f - done[t * 32 + l15];
        float mB = 1.f - done[t * 32 + 16 + l15];
        const float* ha = hsrc + l15 * 256 + q * 8;
        const float* hb = hsrc + (16 + l15) * 256 + q * 8;
        f4v acc0 = (f4v){0.f, 0.f, 0.f, 0.f}, acc1 = (f4v){0.f, 0.f, 0.f, 0.f};
#pragma unroll
        for (int ks = 0; ks < 8; ++ks) {
            float4 x0 = *(const float4*)(ha + ks * 32);
            float4 x1 = *(const float4*)(ha + ks * 32 + 4);
            float4 y0 = *(const float4*)(hb + ks * 32);
            float4 y1 = *(const float4*)(hb + ks * 32 + 4);
            s8v av = pack8s(x0, x1, mA);
            s8v bv = pack8s(y0, y1, mB);
            acc0 = __builtin_amdgcn_mfma_f32_16x16x32_bf16(av, bfr[ks], acc0, 0, 0, 0);
            acc1 = __builtin_amdgcn_mfma_f32_16x16x32_bf16(bv, bfr[ks], acc1, 0, 0, 0);
        }
#pragma unroll
        for (int r = 0; r < 4; ++r) {
            gbuf[g][q * 4 + r][l15] = acc0[r];
            gbuf[g][16 + q * 4 + r][l15] = acc1[r];
        }
        __syncthreads();
        for (int i = threadIdx.x; i < 512; i += 256) {
            int b = i >> 4, u = i & 15;
            int n = hu0 + u;
            const float* gr = gx + (t * 32 + b) * 1024;
            float gi = gbuf[0][b][u] + gr[n];
            float gf = gbuf[1][b][u] + gr[256 + n];
            float gg = gbuf[2][b][u] + gr[512 + n];
            float go = gbuf[3][b][u] + gr[768 + n];
            float m = 1.f - done[t * 32 + b];
            float cm = cst[b][u] * m;
            float cn = sigm(gf) * cm + sigm(gi) * tanhf(gg);
            float hn = sigm(go) * tanhf(cn);
            cst[b][u] = cn;
            hs[t * 8192 + b * 256 + n] = hn;
        }
        if (t < 31) {
            __threadfence();                 // make h-slice stores device-visible
            __syncthreads();                 // all threads' fences done
            if (threadIdx.x == 0) {
                __hip_atomic_fetch_add(cnt, 1u, __ATOMIC_RELEASE, __HIP_MEMORY_SCOPE_AGENT);
                unsigned int target = 16u * (unsigned int)(t + 1);
                while (__hip_atomic_load(cnt, __ATOMIC_ACQUIRE, __HIP_MEMORY_SCOPE_AGENT) < target)
                    __builtin_amdgcn_s_sleep(2);
            }
            __syncthreads();
            __threadfence();                 // acquire side: invalidate stale cache
        } else {
            __syncthreads();
        }
    }
    for (int i = threadIdx.x; i < 512; i += 256) {
        int b = i >> 4, u = i & 15;
        cb[b * 256 + hu0 + u] = cst[b][u];
    }
}

// ---------------- heads (fp32, unchanged) ----------------
__global__ __launch_bounds__(256) void k_heads(const float* __restrict__ hs,
                                               const float* __restrict__ cb,
                                               const float* __restrict__ Wp1, const float* __restrict__ bp1,
                                               const float* __restrict__ Wp2, const float* __restrict__ bp2,
                                               const float* __restrict__ Wv1, const float* __restrict__ bv1,
                                               const float* __restrict__ Wv2, const float* __restrict__ bv2,
                                               float* __restrict__ out) {
    int lane = threadIdx.x & 63;
    int m = blockIdx.x * 4 + (threadIdx.x >> 6);   // 0..1023
    const float4* hv = (const float4*)(hs + m * 256);
    const float4* wp = (const float4*)(Wp1 + lane * 256);
    const float4* wq = (const float4*)(Wv1 + lane * 256);
    float ap = 0.f, av = 0.f;
#pragma unroll 8
    for (int k = 0; k < 64; ++k) {
        float4 h4 = hv[k];
        float4 p4 = wp[k];
        float4 q4 = wq[k];
        ap += h4.x * p4.x + h4.y * p4.y + h4.z * p4.z + h4.w * p4.w;
        av += h4.x * q4.x + h4.y * q4.y + h4.z * q4.z + h4.w * q4.w;
    }
    float hp = tanhf(ap + bp1[lane]);
    float hq = tanhf(av + bv1[lane]);
#pragma unroll
    for (int j = 0; j < 5; ++j) {
        float s = hp * Wp2[j * 64 + lane];
        s += __shfl_xor(s, 1); s += __shfl_xor(s, 2); s += __shfl_xor(s, 4);
        s += __shfl_xor(s, 8); s += __shfl_xor(s, 16); s += __shfl_xor(s, 32);
        if (lane == 0) out[m * 5 + j] = s + bp2[j];
    }
    float s = hq * Wv2[lane];
    s += __shfl_xor(s, 1); s += __shfl_xor(s, 2); s += __shfl_xor(s, 4);
    s += __shfl_xor(s, 8); s += __shfl_xor(s, 16); s += __shfl_xor(s, 32);
    if (lane == 0) out[5120 + m] = s + bv2[0];

    int g = blockIdx.x * 256 + threadIdx.x;
    if (g < 8192) {
        out[6144 + g] = hs[31 * 8192 + g];          // hT
        out[6144 + 8192 + g] = cb[g];               // cT
    }
}

extern "C" void kernel_launch(void* const* d_in, const int* in_sizes, int n_in,
                              void* d_out, int out_size, void* d_ws, size_t ws_size,
                              hipStream_t stream) {
    const float* image = (const float*)d_in[0];
    const int*   act   = (const int*)d_in[1];
    const float* done  = (const float*)d_in[2];
    const float* h0    = (const float*)d_in[3];
    const float* c0    = (const float*)d_in[4];
    const float* W1    = (const float*)d_in[5];
    const float* b1    = (const float*)d_in[6];
    const float* W2    = (const float*)d_in[7];
    const float* b2    = (const float*)d_in[8];
    const float* W3    = (const float*)d_in[9];
    const float* b3    = (const float*)d_in[10];
    const float* Wfc   = (const float*)d_in[11];
    const float* bfc   = (const float*)d_in[12];
    const float* Wih   = (const float*)d_in[13];
    const float* Whh   = (const float*)d_in[14];
    const float* bih   = (const float*)d_in[15];
    const float* bhh   = (const float*)d_in[16];
    const float* Wp1   = (const float*)d_in[17];
    const float* bp1   = (const float*)d_in[18];
    const float* Wp2   = (const float*)d_in[19];
    const float* bp2   = (const float*)d_in[20];
    const float* Wv1   = (const float*)d_in[21];
    const float* bv1   = (const float*)d_in[22];
    const float* Wv2   = (const float*)d_in[23];
    const float* bv2   = (const float*)d_in[24];
    float* out = (float*)d_out;
    char* base = (char*)d_ws;

    // ---- workspace layout (bytes) ----
    unsigned short* a1   = (unsigned short*)(base);             // 26,214,400
    unsigned short* a2   = (unsigned short*)(base + 26214432);  // 10,616,832
    unsigned short* W2p  = (unsigned short*)(base + 36831328);
    unsigned short* W3p  = W2p + 32768;
    unsigned short* Wfcp = W2p + 98304;
    unsigned short* Wihp = W2p + 1703936;
    unsigned short* W1p  = (unsigned short*)(base + 41287776);  // 12,288
    unsigned int*   cnt  = (unsigned int*)(base + 41300064);    // 4
    unsigned short* a3   = (unsigned short*)(base);             // overlays dead a1
    unsigned short* feat = (unsigned short*)(base + 6422528);
    float* gx = (float*)(base + 7471104);
    float* hs = (float*)(base + 11665408);
    float* cb = (float*)(base + 12713984);

    k_prep<<<8728, 256, 0, stream>>>(W2, W3, Wfc, Wih, W1, W2p, W3p, Wfcp, Wihp, W1p);
    k_conv1<<<3200, 256, 0, stream>>>(image, W1p, b1, a1);
    k_conv2<<<648, 256, 0, stream>>>(a1, W2p, b2, a2);
    k_conv3<<<392, 256, 0, stream>>>(a2, W3p, b3, a3);
    k_fc<<<dim3(32, 8), 256, 0, stream>>>(a3, Wfcp, bfc, feat);
    k_gx<<<dim3(32, 16), 256, 0, stream>>>(feat, Wihp, Wih, bih, bhh, act, gx);
    hipMemsetAsync(cnt, 0, 4, stream);
    k_lstm_fused<<<16, 256, 0, stream>>>(h0, c0, done, gx, Whh, hs, cb, cnt);
    k_heads<<<256, 256, 0, stream>>>(hs, cb, Wp1, bp1, Wp2, bp2, Wv1, bv1, Wv2, bv2, out);
}